// Round 2
// baseline (6874.763 us; speedup 1.0000x reference)
//
#include <hip/hip_runtime.h>

// Problem constants (from reference setup_inputs / NUM_POINTS)
#define BATCH 16
#define NPTS  131072
#define NCH   6
#define KSEL  1024
#define MBLK  16                 // blocks per batch
#define TPB   256
#define CHUNK (NPTS / MBLK)      // 8192 points per block
#define PPT   (CHUNK / TPB)      // 32 points per thread
#define DSMEM 81920              // dummy dynamic LDS to force 1 block/CU

// Persistent FPS kernel. One block handles CHUNK points of one batch.
// Cross-block argmax per round via device-scope atomicMax on a packed
// (dist_bits << 32) | ~global_idx key + counter barrier, per-round slots.
//
// Distance arithmetic uses __fsub_rn/__fmul_rn/__fadd_rn so the f32 op
// sequence is bit-identical to the numpy reference (no FMA contraction,
// no reassociation) independent of harness compile flags.
extern "C" __global__ __launch_bounds__(TPB, 1)
void fps_kernel(const float* __restrict__ pts, float* __restrict__ out,
                unsigned long long* __restrict__ best,
                unsigned int* __restrict__ cnt)
{
#pragma clang fp contract(off)
    extern __shared__ float dummy_lds[];     // occupancy limiter (unused)
    __shared__ unsigned long long s_wkey[TPB / 64];
    __shared__ float s_px, s_py, s_pz;

    const int b    = blockIdx.x / MBLK;
    const int m    = blockIdx.x % MBLK;
    const int tid  = threadIdx.x;
    const int base = m * CHUNK;
    const float* __restrict__ pb = pts + (size_t)b * NPTS * NCH;

    // Stage this block's xyz chunk + running min-dists in registers.
    float xr[PPT], yr[PPT], zr[PPT], dmin[PPT];
#pragma unroll
    for (int i = 0; i < PPT; ++i) {
        const float* p = pb + (size_t)(base + tid + i * TPB) * NCH;
        xr[i]   = p[0];
        yr[i]   = p[1];
        zr[i]   = p[2];
        dmin[i] = __builtin_inff();
    }

    // Selected index 0 -> output row 0.
    if (m == 0 && tid < NCH) out[(size_t)b * KSEL * NCH + tid] = pb[tid];

    // p for round 1 is point 0 (uniform scalar loads of read-only data).
    float px = pb[0], py = pb[1], pz = pb[2];

    const int sb = b * KSEL;

    for (int k = 1; k < KSEL; ++k) {
        // ---- update dists + thread-local argmax (first-index tie-break) ----
        float bd = -1.0f;
        int   bj = 0;
#pragma unroll
        for (int i = 0; i < PPT; ++i) {
            // Exact replication of the reference's f32 op sequence:
            // dx=x-px; dx2=dx*dx; d=((dx2+dy2)+dz2). Each op individually
            // rounded (RN), no FMA — __f*_rn are contraction/reassoc-proof.
            float dx = __fsub_rn(xr[i], px);
            float dy = __fsub_rn(yr[i], py);
            float dz = __fsub_rn(zr[i], pz);
            float d  = __fadd_rn(__fadd_rn(__fmul_rn(dx, dx),
                                           __fmul_rn(dy, dy)),
                                 __fmul_rn(dz, dz));
            float dm = dmin[i];
            dm = (d < dm) ? d : dm;
            dmin[i] = dm;
            // j = tid + i*TPB ascends with i, so strict '>' keeps the
            // first (smallest-index) maximum within the thread.
            if (dm > bd) { bd = dm; bj = tid + i * TPB; }
        }

        // ---- wave(64) argmax reduce, smaller index wins ties ----
        for (int off = 32; off > 0; off >>= 1) {
            float od = __shfl_down(bd, off);
            int   oj = __shfl_down(bj, off);
            if (od > bd || (od == bd && oj < bj)) { bd = od; bj = oj; }
        }
        if ((tid & 63) == 0) {
            unsigned gidx = (unsigned)(base + bj);
            s_wkey[tid >> 6] = ((unsigned long long)__float_as_uint(bd) << 32)
                             | (unsigned long long)(unsigned)(~gidx);
        }
        __syncthreads();

        // ---- cross-block reduce + barrier (thread 0 only) ----
        if (tid == 0) {
            unsigned long long key = s_wkey[0];
#pragma unroll
            for (int w = 1; w < TPB / 64; ++w) {
                unsigned long long o = s_wkey[w];
                if (o > key) key = o;
            }
            const int slot = sb + k;
            __hip_atomic_fetch_max(&best[slot], key,
                                   __ATOMIC_RELAXED, __HIP_MEMORY_SCOPE_AGENT);
            __hip_atomic_fetch_add(&cnt[slot], 1u,
                                   __ATOMIC_RELEASE, __HIP_MEMORY_SCOPE_AGENT);
            while (__hip_atomic_load(&cnt[slot], __ATOMIC_ACQUIRE,
                                     __HIP_MEMORY_SCOPE_AGENT) < MBLK) {
                __builtin_amdgcn_s_sleep(1);
            }
            unsigned long long w = __hip_atomic_load(&best[slot], __ATOMIC_RELAXED,
                                                     __HIP_MEMORY_SCOPE_AGENT);
            unsigned gidx = ~(unsigned)(w & 0xFFFFFFFFull);
            const float* pp = pb + (size_t)gidx * NCH;   // read-only input: safe
            s_px = pp[0]; s_py = pp[1]; s_pz = pp[2];
            // round-robin writer emits output row k (all 6 channels)
            if ((k & (MBLK - 1)) == m) {
                float* o = out + ((size_t)b * KSEL + k) * NCH;
#pragma unroll
                for (int c = 0; c < NCH; ++c) o[c] = pp[c];
            }
        }
        __syncthreads();
        px = s_px; py = s_py; pz = s_pz;
    }
}

extern "C" void kernel_launch(void* const* d_in, const int* in_sizes, int n_in,
                              void* d_out, int out_size, void* d_ws, size_t ws_size,
                              hipStream_t stream) {
    const float* pts = (const float*)d_in[0];
    float* out = (float*)d_out;

    // Workspace layout: best[B*K] u64 (128 KB) | cnt[B*K] u32 (64 KB)
    unsigned long long* best = (unsigned long long*)d_ws;
    unsigned int* cnt =
        (unsigned int*)((char*)d_ws + (size_t)BATCH * KSEL * sizeof(unsigned long long));
    size_t init_bytes = (size_t)BATCH * KSEL * (sizeof(unsigned long long) + sizeof(unsigned int));
    hipMemsetAsync(d_ws, 0, init_bytes, stream);   // graph-capturable

    void* args[] = { (void*)&pts, (void*)&out, (void*)&best, (void*)&cnt };
    hipLaunchCooperativeKernel((const void*)fps_kernel,
                               dim3(BATCH * MBLK), dim3(TPB),
                               args, DSMEM, stream);
}

// Round 4
// 5662.540 us; speedup vs baseline: 1.2141x; 1.2141x over previous
//
#include <hip/hip_runtime.h>

// Problem constants (from reference setup_inputs / NUM_POINTS)
#define BATCH 16
#define NPTS  131072
#define NCH   6
#define KSEL  1024
#define MBLK  16                 // blocks per batch
#define TPB   256
#define CHUNK (NPTS / MBLK)      // 8192 points per block
#define PPT   (CHUNK / TPB)      // 32 points per thread
#define DSMEM 81920              // dummy dynamic LDS to force 1 block/CU
#define ROT   4                  // barrier slot rotation depth

// Cross-block sync state in d_ws (memset 0 before launch).
// keys: per-block packed argmax keys, per (batch, round%ROT)
// rec:  broadcast record ((k+1)<<32 | winner_idx), self-contained u64
// arrive: monotonic arrival counters (never reset; target grows per reuse)
struct FpsSync {
    unsigned long long keys[BATCH][ROT][MBLK];   // 8 KB
    unsigned long long rec[BATCH][ROT];          // 512 B
    unsigned int       arrive[BATCH][ROT];       // 256 B
};

// Persistent FPS. One block owns CHUNK points (xyz + running dists in regs).
// Per round: VALU dist update + argmax -> wave/LDS reduce -> relaxed key
// store + ACQ_REL arrival add -> last arriver aggregates 16 keys, publishes
// one relaxed u64 record -> spinners poll relaxed (no per-poll invalidates),
// load winner coords from the read-only input themselves.
extern "C" __global__ __launch_bounds__(TPB, 1)
void fps_kernel(const float* __restrict__ pts, float* __restrict__ out,
                FpsSync* __restrict__ sy)
{
#pragma clang fp contract(off)
    extern __shared__ float dummy_lds[];     // occupancy limiter (unused)
    __shared__ unsigned long long s_wkey[TPB / 64];
    __shared__ float s_px, s_py, s_pz;

    const int b    = blockIdx.x / MBLK;
    const int m    = blockIdx.x % MBLK;
    const int tid  = threadIdx.x;
    const int base = m * CHUNK;
    const float* __restrict__ pb = pts + (size_t)b * NPTS * NCH;

    // Stage this block's xyz chunk + running min-dists in registers.
    float xr[PPT], yr[PPT], zr[PPT], dmin[PPT];
#pragma unroll
    for (int i = 0; i < PPT; ++i) {
        const float* p = pb + (size_t)(base + tid + i * TPB) * NCH;
        xr[i]   = p[0];
        yr[i]   = p[1];
        zr[i]   = p[2];
        dmin[i] = __builtin_inff();
    }

    // Selected index 0 -> output row 0.
    if (m == 0 && tid < NCH) out[(size_t)b * KSEL * NCH + tid] = pb[tid];

    // p for round 1 is point 0 (uniform scalar loads of read-only data).
    float px = pb[0], py = pb[1], pz = pb[2];

    for (int k = 1; k < KSEL; ++k) {
        // ---- update dists + thread-local argmax (first-index tie-break) ----
        float bd = -1.0f;
        int   bj = 0;
#pragma unroll
        for (int i = 0; i < PPT; ++i) {
            // Bit-exact replication of the reference's f32 op sequence:
            // each op individually rounded (RN), no FMA / no reassociation.
            float dx = __fsub_rn(xr[i], px);
            float dy = __fsub_rn(yr[i], py);
            float dz = __fsub_rn(zr[i], pz);
            float d  = __fadd_rn(__fadd_rn(__fmul_rn(dx, dx),
                                           __fmul_rn(dy, dy)),
                                 __fmul_rn(dz, dz));
            float dm = dmin[i];
            dm = (d < dm) ? d : dm;
            dmin[i] = dm;
            // j = tid + i*TPB ascends with i: strict '>' keeps first index.
            if (dm > bd) { bd = dm; bj = tid + i * TPB; }
        }

        // ---- wave(64) argmax reduce, smaller index wins ties ----
        for (int off = 32; off > 0; off >>= 1) {
            float od = __shfl_down(bd, off);
            int   oj = __shfl_down(bj, off);
            if (od > bd || (od == bd && oj < bj)) { bd = od; bj = oj; }
        }
        if ((tid & 63) == 0) {
            unsigned gidx = (unsigned)(base + bj);
            s_wkey[tid >> 6] = ((unsigned long long)__float_as_uint(bd) << 32)
                             | (unsigned long long)(unsigned)(~gidx);
        }
        __syncthreads();

        // ---- cross-block barrier + broadcast (thread 0 only) ----
        if (tid == 0) {
            unsigned long long key = s_wkey[0];
#pragma unroll
            for (int w = 1; w < TPB / 64; ++w) {
                unsigned long long o = s_wkey[w];
                if (o > key) key = o;
            }
            const int s = k & (ROT - 1);
            // Publish this block's key (relaxed store; ordered before the
            // arrival add by the add's RELEASE half).
            __hip_atomic_store(&sy->keys[b][s][m], key,
                               __ATOMIC_RELAXED, __HIP_MEMORY_SCOPE_AGENT);
            unsigned old = __hip_atomic_fetch_add(&sy->arrive[b][s], 1u,
                                                  __ATOMIC_ACQ_REL,
                                                  __HIP_MEMORY_SCOPE_AGENT);
            // Monotonic target. Use-index of round k in slot s is
            // ceil(k/ROT) = ((k-1)>>2)+1  (loop starts at k=1: slot 0's
            // first use is k=4 -> index 1, NOT 2 — the R3 deadlock bug).
            const unsigned target = (((unsigned)(k - 1) >> 2) + 1u) * MBLK;
            unsigned gidx;
            if (old == target - 1u) {
                // Last arriver: all 15 other key stores are visible
                // (their RELEASE adds precede ours in coherence order,
                // our add has ACQUIRE). Gather + local max.
                unsigned long long mx = key;
#pragma unroll
                for (int w = 0; w < MBLK; ++w) {
                    unsigned long long o = __hip_atomic_load(
                        &sy->keys[b][s][w], __ATOMIC_RELAXED,
                        __HIP_MEMORY_SCOPE_AGENT);
                    if (o > mx) mx = o;
                }
                gidx = ~(unsigned)(mx & 0xFFFFFFFFull);
                // Self-contained broadcast record: no release drain needed.
                unsigned long long rec =
                    ((unsigned long long)(unsigned)(k + 1) << 32)
                    | (unsigned long long)gidx;
                __hip_atomic_store(&sy->rec[b][s], rec,
                                   __ATOMIC_RELAXED, __HIP_MEMORY_SCOPE_AGENT);
                // Output row k (off the spinners' critical path).
                const float* pp = pb + (size_t)gidx * NCH;
                float* o = out + ((size_t)b * KSEL + k) * NCH;
#pragma unroll
                for (int c = 0; c < NCH; ++c) o[c] = pp[c];
            } else {
                // Relaxed polling: no per-poll cache invalidates. Stale
                // records can't false-match (tag k+1 is unique per slot use).
                const unsigned want = (unsigned)(k + 1);
                unsigned long long r;
                do {
                    r = __hip_atomic_load(&sy->rec[b][s], __ATOMIC_RELAXED,
                                          __HIP_MEMORY_SCOPE_AGENT);
                } while ((unsigned)(r >> 32) != want);
                gidx = (unsigned)(r & 0xFFFFFFFFull);
            }
            // Winner coords from the read-only input (plain loads: any
            // cached copy is valid since pts is never written).
            const float* pp = pb + (size_t)gidx * NCH;
            s_px = pp[0]; s_py = pp[1]; s_pz = pp[2];
        }
        __syncthreads();
        px = s_px; py = s_py; pz = s_pz;
    }
}

extern "C" void kernel_launch(void* const* d_in, const int* in_sizes, int n_in,
                              void* d_out, int out_size, void* d_ws, size_t ws_size,
                              hipStream_t stream) {
    const float* pts = (const float*)d_in[0];
    float* out = (float*)d_out;
    FpsSync* sy = (FpsSync*)d_ws;

    hipMemsetAsync(d_ws, 0, sizeof(FpsSync), stream);   // graph-capturable

    void* args[] = { (void*)&pts, (void*)&out, (void*)&sy };
    hipLaunchCooperativeKernel((const void*)fps_kernel,
                               dim3(BATCH * MBLK), dim3(TPB),
                               args, DSMEM, stream);
}

// Round 6
// 2918.764 us; speedup vs baseline: 2.3554x; 1.9400x over previous
//
#include <hip/hip_runtime.h>

// Problem constants (from reference setup_inputs / NUM_POINTS)
#define BATCH 16
#define NPTS  131072
#define NCH   6
#define KSEL  1024
#define MBLK  16                 // blocks per batch
#define TPB   256
#define CHUNK (NPTS / MBLK)      // 8192 points per block
#define PPT   (CHUNK / TPB)      // 32 points per thread
#define DSMEM 81920              // dummy dynamic LDS -> 1 block/CU (proven cfg)
#define ROT   2                  // slot rotation depth (double buffer)

// pub[BATCH][ROT][MBLK] u64 (4 KB), memset 0 before launch.
// Word: [dist_f32_bits:32][~idx:20][tag:12], tag = round k (1..1023 —
// 12-bit field never wraps; memset tag 0 never matches any polled round).
// All stores/loads RELAXED agent scope (proven working in R4's rec-poll).
// u64 order: max dist first, then max ~idx = min global index — exactly
// jnp.argmax first-occurrence tie-break.
// ROT=2 overwrite safety (causal): block A first overwrites slot (k&1) at
// round k+2, which requires A observed every block's round-(k+1) word; each
// block publishes k+1 only after finishing its round-k poll reads.

extern "C" __global__ __launch_bounds__(TPB, 1)
void fps_kernel(const float* __restrict__ pts, float* __restrict__ out,
                unsigned long long* __restrict__ pub)
{
#pragma clang fp contract(off)
    extern __shared__ float dummy_lds[];     // occupancy limiter (unused)
    __shared__ float              s_wd[TPB / 64];
    __shared__ int                s_wi[TPB / 64];
    __shared__ unsigned long long s_key[MBLK];
    __shared__ float              s_px, s_py, s_pz;

    const int b    = blockIdx.x / MBLK;
    const int m    = blockIdx.x % MBLK;
    const int tid  = threadIdx.x;
    const int base = m * CHUNK;
    const float* __restrict__ pb = pts + (size_t)b * NPTS * NCH;

    // Stage this block's xyz chunk + running min-dists in registers.
    float xr[PPT], yr[PPT], zr[PPT], dmin[PPT];
#pragma unroll
    for (int i = 0; i < PPT; ++i) {
        const float* p = pb + (size_t)(base + tid + i * TPB) * NCH;
        xr[i]   = p[0];
        yr[i]   = p[1];
        zr[i]   = p[2];
        dmin[i] = __builtin_inff();
    }

    // Selected index 0 -> output row 0.
    if (m == 0 && tid < NCH) out[(size_t)b * KSEL * NCH + tid] = pb[tid];

    // p for round 1 is point 0 (uniform scalar loads of read-only data).
    float px = pb[0], py = pb[1], pz = pb[2];

    for (int k = 1; k < KSEL; ++k) {
        // ---- dist update + thread-local argmax (first-index tie-break) ----
        float bd = -1.0f;
        int   bj = 0;
#pragma unroll
        for (int i = 0; i < PPT; ++i) {
            // Bit-exact replication of the reference's f32 op sequence:
            // each op individually rounded (RN), no FMA / no reassociation.
            float dx = __fsub_rn(xr[i], px);
            float dy = __fsub_rn(yr[i], py);
            float dz = __fsub_rn(zr[i], pz);
            float d  = __fadd_rn(__fadd_rn(__fmul_rn(dx, dx),
                                           __fmul_rn(dy, dy)),
                                 __fmul_rn(dz, dz));
            float dm = dmin[i];
            dm = (d < dm) ? d : dm;
            dmin[i] = dm;
            // j = tid + i*TPB ascends with i: strict '>' keeps first index.
            if (dm > bd) { bd = dm; bj = tid + i * TPB; }
        }

        // ---- wave(64) argmax reduce, smaller index wins ties ----
        for (int off = 32; off > 0; off >>= 1) {
            float od = __shfl_down(bd, off);
            int   oj = __shfl_down(bj, off);
            if (od > bd || (od == bd && oj < bj)) { bd = od; bj = oj; }
        }
        if ((tid & 63) == 0) {
            const int w = tid >> 6;
            s_wd[w] = bd; s_wi[w] = bj;
        }
        __syncthreads();                                   // [A]

        unsigned long long* slot =
            pub + ((size_t)b * ROT + (size_t)(k & (ROT - 1))) * MBLK;

        // ---- publish this block's tagged key (tid 0) ----
        if (tid == 0) {
            float fd = s_wd[0]; int fi = s_wi[0];
#pragma unroll
            for (int w = 1; w < TPB / 64; ++w) {
                if (s_wd[w] > fd || (s_wd[w] == fd && s_wi[w] < fi)) {
                    fd = s_wd[w]; fi = s_wi[w];
                }
            }
            const unsigned g   = (unsigned)(base + fi);
            const unsigned inv = 0xFFFFFu ^ g;             // 20-bit ~idx
            unsigned long long key =
                ((unsigned long long)__float_as_uint(fd) << 32)
                | ((unsigned long long)inv << 12)
                | (unsigned long long)(unsigned)k;         // 12-bit tag
            __hip_atomic_store(&slot[m], key, __ATOMIC_RELAXED,
                               __HIP_MEMORY_SCOPE_AGENT);
        }

        // ---- parallel poll: lane j waits for block j's word ----
        if (tid < MBLK) {
            unsigned long long v;
            do {
                v = __hip_atomic_load(&slot[tid], __ATOMIC_RELAXED,
                                      __HIP_MEMORY_SCOPE_AGENT);
            } while ((unsigned)(v & 0xFFFull) != (unsigned)k);
            s_key[tid] = v;
        }
        __syncthreads();                                   // [B]

        // ---- cross-block reduce + winner fetch (tid 0) ----
        if (tid == 0) {
            unsigned long long mx = s_key[0];
#pragma unroll
            for (int w = 1; w < MBLK; ++w) {
                if (s_key[w] > mx) mx = s_key[w];
            }
            const unsigned g = 0xFFFFFu ^ (unsigned)((mx >> 12) & 0xFFFFFull);
            const float* pp = pb + (size_t)g * NCH;  // read-only input: safe
            s_px = pp[0]; s_py = pp[1]; s_pz = pp[2];
            // Round-robin writer block emits output row k.
            if ((k & (MBLK - 1)) == m) {
                float* o = out + ((size_t)b * KSEL + k) * NCH;
#pragma unroll
                for (int c = 0; c < NCH; ++c) o[c] = pp[c];
            }
        }
        __syncthreads();                                   // [C]
        px = s_px; py = s_py; pz = s_pz;
    }
}

extern "C" void kernel_launch(void* const* d_in, const int* in_sizes, int n_in,
                              void* d_out, int out_size, void* d_ws, size_t ws_size,
                              hipStream_t stream) {
    const float* pts = (const float*)d_in[0];
    float* out = (float*)d_out;
    unsigned long long* pub = (unsigned long long*)d_ws;

    // pub[BATCH][ROT][MBLK] u64 = 4 KB; zero -> all tags 0 (never match).
    hipMemsetAsync(d_ws, 0,
                   (size_t)BATCH * ROT * MBLK * sizeof(unsigned long long),
                   stream);

    void* args[] = { (void*)&pts, (void*)&out, (void*)&pub };
    hipLaunchCooperativeKernel((const void*)fps_kernel,
                               dim3(BATCH * MBLK), dim3(TPB),
                               args, DSMEM, stream);
}